// Round 15
// baseline (206.791 us; speedup 1.0000x reference)
//
#include <hip/hip_runtime.h>
#include <stdint.h>

// LIF spike encoder — two-phase, bit-exact fp32.
//   Dense history: R6 154 | R13 168.4 total (dense ~108, best; x-reg banks) |
//   R14 192 (lockstep barriers = R9 redux). Dense is L2-latency-bound at
//   ~105-125 regardless of bytes/x-path/sharing (R10-R14).
//   R15 (this): reclaim dead time instead of pushing dense further.
//   (1) Kernel1 = dense (512 blocks) + zero-fill of frames t>=2 (512 blocks,
//       264 MB) in ONE kernel: dense is latency-bound w/ tiny HBM traffic,
//       fill is pure HBM write -> pipes overlap. No LDS anywhere in kernel1
//       so both block kinds co-reside freely.
//   (2) Dense: R13 bank structure, x banks from GLOBAL (wave-uniform float4,
//       L1 broadcast, prefetched a half ahead). Swizzle PARITY FIX:
//       n_tile = xcd*2 + (w&1), m_tile = w>>1 -> co-resident pair (w, w+32)
//       shares the n-slice -> 4 waves/CU stream identical W lines (L1 dedup).
//   (3) Kernel2 = recurrence, early-return on cnt==0 (tail pre-zeroed).
// Bit-exactness: each output = ONE register, one fmaf per k, k=0..2047
// ascending — identical chain to all passing rounds. Sparse phase: ordered
// adds over sorted spike list == dense chain exactly.

#define BATCHSZ 256
#define NU      2048
#define TSTEPS  128
#define BLK     1024
#define NWAVES  (BLK / 64)
#define BN_FR   (BATCHSZ * NU)              // floats per time-frame

// ---------------- Kernel 1: dense GEMM (t=1) + zero-fill tail --------------
#define D_BN 128
#define D_BM 8
#define D_DENSE_BLOCKS 512
#define D_FILL_BLOCKS  512

__global__ __launch_bounds__(128) void lif_dense_fill(
    const float* __restrict__ x,
    const float* __restrict__ W,
    float* __restrict__ ws,
    float* __restrict__ out)
{
    const int bid = blockIdx.x;
    const int tid = threadIdx.x;

    if (bid >= D_DENSE_BLOCKS) {
        // ---- fill blocks: zero frames t = 2..127 (126*BN_FR floats)
        const int    fid    = bid - D_DENSE_BLOCKS;
        float4*      dst    = (float4*)(out + (size_t)2 * BN_FR);
        const int    total  = (TSTEPS - 2) * BN_FR / 4;     // float4 count
        const int    stride = D_FILL_BLOCKS * 128;
        float4 zz; zz.x = zz.y = zz.z = zz.w = 0.0f;
        for (int i = fid * 128 + tid; i < total; i += stride)
            dst[i] = zz;
        return;
    }

    // ---- dense blocks
    const int lane = tid & 63;
    const int xcd    = bid & 7;             // XCD-local W slice (2 MB, L2)
    const int w      = bid >> 3;            // 0..63 within XCD
    const int n_tile = xcd * 2 + (w & 1);   // PARITY: pair (w, w+32) shares
    const int m_tile = w >> 1;              // 0..31
    const int n0     = n_tile * D_BN;
    const int m0     = m_tile * D_BM;

    const int rb = (tid >> 6) * 4;          // wave row base: 0 or 4
    const float* xw = x + (size_t)(m0 + rb) * NU;  // wave-uniform row base
    const float* wp = W + n0 + lane * 2;    // this thread's 2 cols

    float2 wA[16], wB[16];                  // W banks (16 k each)
    float4 xA[16], xB[16];                  // x banks: [q*4+r] = row r, 4 k
    float2 acc[4];
    #pragma unroll
    for (int r = 0; r < 4; ++r) { acc[r].x = 0.0f; acc[r].y = 0.0f; }

    // prologue: half 0 into A banks
    #pragma unroll
    for (int j = 0; j < 16; ++j)
        wA[j] = *(const float2*)(wp + (size_t)j * NU);
    #pragma unroll
    for (int q = 0; q < 4; ++q)
        #pragma unroll
        for (int r = 0; r < 4; ++r)
            xA[q * 4 + r] = *(const float4*)(xw + (size_t)r * NU + q * 4);

    for (int k0 = 0; k0 < NU; k0 += 32) {
        // ---- prefetch half (k0+16) into B banks
        #pragma unroll
        for (int j = 0; j < 16; ++j)
            wB[j] = *(const float2*)(wp + (size_t)(k0 + 16 + j) * NU);
        #pragma unroll
        for (int q = 0; q < 4; ++q)
            #pragma unroll
            for (int r = 0; r < 4; ++r)
                xB[q * 4 + r] = *(const float4*)(xw + (size_t)r * NU + k0 + 16 + q * 4);

        // ---- compute half k0 from A banks
        #pragma unroll
        for (int q = 0; q < 4; ++q)
            #pragma unroll
            for (int kk = 0; kk < 4; ++kk) {
                float2 wv = wA[q * 4 + kk];
                #pragma unroll
                for (int r = 0; r < 4; ++r) {
                    float xv = ((const float*)&xA[q * 4 + r])[kk];
                    acc[r].x = __builtin_fmaf(xv, wv.x, acc[r].x);
                    acc[r].y = __builtin_fmaf(xv, wv.y, acc[r].y);
                }
            }

        // ---- prefetch half (k0+32) into A banks
        if (k0 + 32 < NU) {
            #pragma unroll
            for (int j = 0; j < 16; ++j)
                wA[j] = *(const float2*)(wp + (size_t)(k0 + 32 + j) * NU);
            #pragma unroll
            for (int q = 0; q < 4; ++q)
                #pragma unroll
                for (int r = 0; r < 4; ++r)
                    xA[q * 4 + r] = *(const float4*)(xw + (size_t)r * NU + k0 + 32 + q * 4);
        }

        // ---- compute half k0+16 from B banks
        #pragma unroll
        for (int q = 0; q < 4; ++q)
            #pragma unroll
            for (int kk = 0; kk < 4; ++kk) {
                float2 wv = wB[q * 4 + kk];
                #pragma unroll
                for (int r = 0; r < 4; ++r) {
                    float xv = ((const float*)&xB[q * 4 + r])[kk];
                    acc[r].x = __builtin_fmaf(xv, wv.x, acc[r].x);
                    acc[r].y = __builtin_fmaf(xv, wv.y, acc[r].y);
                }
            }
    }

    #pragma unroll
    for (int r = 0; r < 4; ++r)
        *(float2*)&ws[(size_t)(m0 + rb + r) * NU + n0 + lane * 2] = acc[r];
}

// ---------------- Kernel 2: recurrence from t=2 (tail pre-zeroed) ----------
__global__ __launch_bounds__(BLK) void lif_recurrence(
    const float* __restrict__ x,
    const float* __restrict__ W,
    const float* __restrict__ V1,
    float* __restrict__ out)
{
    const int b    = blockIdx.x;
    const int tid  = threadIdx.x;
    const int lane = tid & 63;
    const int wid  = tid >> 6;

    __shared__ int           s_idx[NU];      // spiking row offsets (k*NU)
    __shared__ unsigned char s_flag[NU];
    __shared__ int           s_wsum[NWAVES];
    __shared__ int           s_cnt;

    const int n0 = tid;
    const int n1 = tid + BLK;

    float* outb = out + (size_t)b * TSTEPS * NU;   // (B, T, N)

    float V0, V1r;
    int   z0, z1;
    {
        float x0 = x[(size_t)b * NU + n0];
        float x1 = x[(size_t)b * NU + n1];
        outb[n0] = x0;
        outb[n1] = x1;
        V0  = V1[(size_t)b * NU + n0];
        V1r = V1[(size_t)b * NU + n1];
        z0 = V0  > 1.0f;
        z1 = V1r > 1.0f;
        float* f1 = outb + NU;
        f1[n0] = z0 ? 1.0f : 0.0f;
        f1[n1] = z1 ? 1.0f : 0.0f;
        s_flag[n0] = (unsigned char)z0;
        s_flag[n1] = (unsigned char)z1;
    }
    __syncthreads();

    for (int t = 2; t < TSTEPS; ++t) {
        int f0 = s_flag[2 * tid];
        int f1 = s_flag[2 * tid + 1];
        int c  = f0 + f1;
        int v  = c;
        #pragma unroll
        for (int d = 1; d < 64; d <<= 1) {
            int o = __shfl_up(v, d);
            if (lane >= d) v += o;
        }
        if (lane == 63) s_wsum[wid] = v;
        __syncthreads();
        int base = 0;
        #pragma unroll
        for (int w = 0; w < NWAVES; ++w) base += (w < wid) ? s_wsum[w] : 0;
        int off = base + v - c;                   // exclusive prefix
        if (f0) s_idx[off++] = (2 * tid) * NU;
        if (f1) s_idx[off]   = (2 * tid + 1) * NU;
        if (tid == BLK - 1) s_cnt = base + v;
        __syncthreads();

        int cnt = s_cnt;
        if (cnt == 0) return;               // tail frames pre-zeroed (kernel 1)

        float I0 = 0.0f, I1 = 0.0f;
        const float* Wc = W + tid;
        int i = 0;
        for (; i + 4 <= cnt; i += 4) {
            const float* r0 = Wc + s_idx[i];
            const float* r1 = Wc + s_idx[i + 1];
            const float* r2 = Wc + s_idx[i + 2];
            const float* r3 = Wc + s_idx[i + 3];
            float a0 = r0[0], b0 = r0[BLK];
            float a1 = r1[0], b1 = r1[BLK];
            float a2 = r2[0], b2 = r2[BLK];
            float a3 = r3[0], b3 = r3[BLK];
            I0 += a0; I0 += a1; I0 += a2; I0 += a3;   // order preserved
            I1 += b0; I1 += b1; I1 += b2; I1 += b3;
        }
        for (; i < cnt; ++i) {
            const float* r = Wc + s_idx[i];
            I0 += r[0];
            I1 += r[BLK];
        }

        float d0 = 0.90483741803595952f * V0;     // one rounding
        float d1 = 0.90483741803595952f * V1r;
        asm volatile("" : "+v"(d0), "+v"(d1));    // forbid fma-contraction
        float nv0 = (z0 ? 0.0f : d0) + I0;        // one rounding
        float nv1 = (z1 ? 0.0f : d1) + I1;
        V0 = nv0; V1r = nv1;
        z0 = nv0 > 1.0f;
        z1 = nv1 > 1.0f;

        float* po = outb + (size_t)t * NU;
        po[n0] = z0 ? 1.0f : 0.0f;
        po[n1] = z1 ? 1.0f : 0.0f;
        s_flag[n0] = (unsigned char)z0;
        s_flag[n1] = (unsigned char)z1;
        __syncthreads();
    }
}

// ---------------- Fallback: round-4 fused kernel (proven) ------------------
__global__ __launch_bounds__(BLK) void lif_fused(
    const float* __restrict__ x,
    const float* __restrict__ W,
    float* __restrict__ out)
{
    const int b    = blockIdx.x;
    const int tid  = threadIdx.x;
    const int lane = tid & 63;
    const int wid  = tid >> 6;

    __shared__ float         s_x[NU];
    __shared__ int           s_idx[NU];
    __shared__ unsigned char s_flag[NU];
    __shared__ int           s_wsum[NWAVES];
    __shared__ int           s_cnt;

    const int n0 = tid;
    const int n1 = tid + BLK;
    float* outb = out + (size_t)b * TSTEPS * NU;

    {
        float x0 = x[(size_t)b * NU + n0];
        float x1 = x[(size_t)b * NU + n1];
        s_x[n0] = x0; s_x[n1] = x1;
        outb[n0] = x0; outb[n1] = x1;
    }
    __syncthreads();

    float I0 = 0.0f, I1 = 0.0f;
    {
        const float* Wc = W + tid;
        #pragma unroll 8
        for (int k = 0; k < NU; ++k) {
            float xk = s_x[k];
            const float* wr = Wc + (size_t)k * NU;
            I0 = __builtin_fmaf(xk, wr[0],   I0);
            I1 = __builtin_fmaf(xk, wr[BLK], I1);
        }
    }

    float V0 = 0.0f, V1 = 0.0f;
    int   z0 = 0,    z1 = 0;

    for (int t = 1; t < TSTEPS; ++t) {
        if (t >= 2) {
            int f0 = s_flag[2 * tid];
            int f1 = s_flag[2 * tid + 1];
            int c  = f0 + f1;
            int v  = c;
            #pragma unroll
            for (int d = 1; d < 64; d <<= 1) {
                int o = __shfl_up(v, d);
                if (lane >= d) v += o;
            }
            if (lane == 63) s_wsum[wid] = v;
            __syncthreads();
            int base = 0;
            #pragma unroll
            for (int w = 0; w < NWAVES; ++w) base += (w < wid) ? s_wsum[w] : 0;
            int off = base + v - c;
            if (f0) s_idx[off++] = 2 * tid;
            if (f1) s_idx[off]   = 2 * tid + 1;
            if (tid == BLK - 1) s_cnt = base + v;
            __syncthreads();

            int cnt = s_cnt;
            if (cnt == 0) {
                size_t  elems  = (size_t)(TSTEPS - t) * NU;
                float4* p      = (float4*)(outb + (size_t)t * NU);
                int     chunks = (int)(elems / 4);
                float4  zz; zz.x = zz.y = zz.z = zz.w = 0.0f;
                for (int i = tid; i < chunks; i += BLK) p[i] = zz;
                return;
            }

            I0 = 0.0f; I1 = 0.0f;
            const float* Wc = W + tid;
            int i = 0;
            for (; i + 2 <= cnt; i += 2) {
                const float* r0 = Wc + (size_t)s_idx[i]     * NU;
                const float* r1 = Wc + (size_t)s_idx[i + 1] * NU;
                float a0 = r0[0], b0 = r0[BLK];
                float a1 = r1[0], b1 = r1[BLK];
                I0 += a0; I0 += a1;
                I1 += b0; I1 += b1;
            }
            for (; i < cnt; ++i) {
                const float* r = Wc + (size_t)s_idx[i] * NU;
                I0 += r[0];
                I1 += r[BLK];
            }
        }

        float d0 = 0.90483741803595952f * V0;
        float d1 = 0.90483741803595952f * V1;
        asm volatile("" : "+v"(d0), "+v"(d1));
        float nv0 = (z0 ? 0.0f : d0) + I0;
        float nv1 = (z1 ? 0.0f : d1) + I1;
        V0 = nv0; V1 = nv1;
        z0 = nv0 > 1.0f;
        z1 = nv1 > 1.0f;

        float* po = outb + (size_t)t * NU;
        po[n0] = z0 ? 1.0f : 0.0f;
        po[n1] = z1 ? 1.0f : 0.0f;
        s_flag[n0] = (unsigned char)z0;
        s_flag[n1] = (unsigned char)z1;
        __syncthreads();
    }
}

extern "C" void kernel_launch(void* const* d_in, const int* in_sizes, int n_in,
                              void* d_out, int out_size, void* d_ws, size_t ws_size,
                              hipStream_t stream) {
    const float* x = (const float*)d_in[0];   // (256, 2048) fp32
    const float* W = (const float*)d_in[1];   // (2048, 2048) fp32
    if (n_in >= 2 && in_sizes[0] == NU * NU && in_sizes[1] == BATCHSZ * NU) {
        const float* t = x; x = W; W = t;     // defensive input-order swap
    }
    float* out = (float*)d_out;               // (B, T, N) fp32

    const size_t need = (size_t)BATCHSZ * NU * sizeof(float);   // 2 MB
    if (ws_size >= need) {
        float* V1 = (float*)d_ws;
        hipLaunchKernelGGL(lif_dense_fill,
                           dim3(D_DENSE_BLOCKS + D_FILL_BLOCKS), dim3(128),
                           0, stream, x, W, V1, out);
        hipLaunchKernelGGL(lif_recurrence,
                           dim3(BATCHSZ), dim3(BLK), 0, stream,
                           x, W, V1, out);
    } else {
        hipLaunchKernelGGL(lif_fused, dim3(BATCHSZ), dim3(BLK), 0, stream,
                           x, W, out);
    }
}

// Round 16
// 175.892 us; speedup vs baseline: 1.1757x; 1.1757x over previous
//
#include <hip/hip_runtime.h>
#include <stdint.h>

// LIF spike encoder — two-phase, bit-exact fp32.
//   R13 = 168.4 us total (best): dense ~108 (L2-service/latency-bound),
//   recurrence ~60. R14 (lockstep barriers) 192; R15 (fill+dense mixed) 207 —
//   write-flood thrashes the L2 queues the latency-bound dense needs. Revert.
//   R16 (this): R13 VERBATIM except the grid swizzle parity fix:
//     n_tile = xcd*2 + (w&1), m_tile = w>>1
//   so the co-resident block pair (w, w+32) on one CU shares ONE n-slice ->
//   all 4 waves/CU issue IDENTICAL W addresses -> L1/MSHR merge halves the
//   unique L2 traffic (64 -> 32 MB/XCD). Clean A/B vs R13.
// Bit-exactness: each output = ONE register, one fmaf per k, k=0..2047
// ascending — identical chain to all passing rounds. Sparse phase: ordered
// adds over sorted spike list == dense chain exactly.

#define BATCHSZ 256
#define NU      2048
#define TSTEPS  128
#define BLK     1024
#define NWAVES  (BLK / 64)

// ---------------- Phase A: dense GEMM (t=1), bit-exact chain ----------------
// 512 blocks x 128 thr; BM=8 (4 rows/wave) x BN=128 (2 cols/lane, float2).
#define D_BN 128
#define D_BM 8

__global__ __launch_bounds__(128) void lif_dense_v1(
    const float* __restrict__ x,
    const float* __restrict__ W,
    float* __restrict__ ws)
{
    __shared__ float s_x[D_BM * NU];        // 64 KB: the block's 8 x-rows

    const int tid  = threadIdx.x;
    const int lane = tid & 63;

    // swizzle: xcd = bid&7 keeps the XCD-local 2 MB W slice; PARITY maps the
    // co-resident pair (w, w+32) to the SAME n-slice for L1/MSHR dedup.
    const int bid    = blockIdx.x;
    const int xcd    = bid & 7;
    const int w      = bid >> 3;            // 0..63 within XCD
    const int n_tile = xcd * 2 + (w & 1);   // 0..15
    const int m_tile = w >> 1;              // 0..31
    const int n0     = n_tile * D_BN;
    const int m0     = m_tile * D_BM;

    // ---- stage 8 contiguous x rows (flat float4 copy, coalesced)
    {
        const float4* xg = (const float4*)(x + (size_t)m0 * NU);
        float4*       xs = (float4*)s_x;
        #pragma unroll
        for (int j = 0; j < 32; ++j)        // 4096 float4 / 128 threads
            xs[j * 128 + tid] = xg[j * 128 + tid];
    }
    __syncthreads();

    const int rb = (tid >> 6) * 4;          // wave row base: 0 or 4
    const float* xw = &s_x[rb * NU];        // this wave's 4 rows (LDS)
    const float* wp = W + n0 + lane * 2;    // this thread's 2 cols

    float2 wA[16], wB[16];                  // W banks (16 k each)
    float4 xA[16], xB[16];                  // x banks: [q*4+r] = rows r, 4 k
    float2 acc[4];
    #pragma unroll
    for (int r = 0; r < 4; ++r) { acc[r].x = 0.0f; acc[r].y = 0.0f; }

    // prologue: load half 0 into A banks
    #pragma unroll
    for (int j = 0; j < 16; ++j)
        wA[j] = *(const float2*)(wp + (size_t)j * NU);
    #pragma unroll
    for (int q = 0; q < 4; ++q)
        #pragma unroll
        for (int r = 0; r < 4; ++r)
            xA[q * 4 + r] = *(const float4*)&xw[r * NU + q * 4];

    for (int k0 = 0; k0 < NU; k0 += 32) {
        // ---- prefetch half (k0+16) into B banks
        #pragma unroll
        for (int j = 0; j < 16; ++j)
            wB[j] = *(const float2*)(wp + (size_t)(k0 + 16 + j) * NU);
        #pragma unroll
        for (int q = 0; q < 4; ++q)
            #pragma unroll
            for (int r = 0; r < 4; ++r)
                xB[q * 4 + r] = *(const float4*)&xw[r * NU + k0 + 16 + q * 4];

        // ---- compute half k0 from A banks (zero load-use waits inside)
        #pragma unroll
        for (int q = 0; q < 4; ++q)
            #pragma unroll
            for (int kk = 0; kk < 4; ++kk) {
                float2 wv = wA[q * 4 + kk];
                #pragma unroll
                for (int r = 0; r < 4; ++r) {
                    float xv = ((const float*)&xA[q * 4 + r])[kk];
                    acc[r].x = __builtin_fmaf(xv, wv.x, acc[r].x);
                    acc[r].y = __builtin_fmaf(xv, wv.y, acc[r].y);
                }
            }

        // ---- prefetch half (k0+32) into A banks
        if (k0 + 32 < NU) {
            #pragma unroll
            for (int j = 0; j < 16; ++j)
                wA[j] = *(const float2*)(wp + (size_t)(k0 + 32 + j) * NU);
            #pragma unroll
            for (int q = 0; q < 4; ++q)
                #pragma unroll
                for (int r = 0; r < 4; ++r)
                    xA[q * 4 + r] = *(const float4*)&xw[r * NU + k0 + 32 + q * 4];
        }

        // ---- compute half k0+16 from B banks
        #pragma unroll
        for (int q = 0; q < 4; ++q)
            #pragma unroll
            for (int kk = 0; kk < 4; ++kk) {
                float2 wv = wB[q * 4 + kk];
                #pragma unroll
                for (int r = 0; r < 4; ++r) {
                    float xv = ((const float*)&xB[q * 4 + r])[kk];
                    acc[r].x = __builtin_fmaf(xv, wv.x, acc[r].x);
                    acc[r].y = __builtin_fmaf(xv, wv.y, acc[r].y);
                }
            }
    }

    #pragma unroll
    for (int r = 0; r < 4; ++r)
        *(float2*)&ws[(size_t)(m0 + rb + r) * NU + n0 + lane * 2] = acc[r];
}

// ---------------- Phase B: recurrence from t=2 (unchanged, proven) ---------
__global__ __launch_bounds__(BLK) void lif_recurrence(
    const float* __restrict__ x,
    const float* __restrict__ W,
    const float* __restrict__ V1,
    float* __restrict__ out)
{
    const int b    = blockIdx.x;
    const int tid  = threadIdx.x;
    const int lane = tid & 63;
    const int wid  = tid >> 6;

    __shared__ int           s_idx[NU];      // spiking row offsets (k*NU)
    __shared__ unsigned char s_flag[NU];
    __shared__ int           s_wsum[NWAVES];
    __shared__ int           s_cnt;

    const int n0 = tid;
    const int n1 = tid + BLK;

    float* outb = out + (size_t)b * TSTEPS * NU;   // (B, T, N)

    float V0, V1r;
    int   z0, z1;
    {
        float x0 = x[(size_t)b * NU + n0];
        float x1 = x[(size_t)b * NU + n1];
        outb[n0] = x0;
        outb[n1] = x1;
        V0  = V1[(size_t)b * NU + n0];
        V1r = V1[(size_t)b * NU + n1];
        z0 = V0  > 1.0f;
        z1 = V1r > 1.0f;
        float* f1 = outb + NU;
        f1[n0] = z0 ? 1.0f : 0.0f;
        f1[n1] = z1 ? 1.0f : 0.0f;
        s_flag[n0] = (unsigned char)z0;
        s_flag[n1] = (unsigned char)z1;
    }
    __syncthreads();

    for (int t = 2; t < TSTEPS; ++t) {
        int f0 = s_flag[2 * tid];
        int f1 = s_flag[2 * tid + 1];
        int c  = f0 + f1;
        int v  = c;
        #pragma unroll
        for (int d = 1; d < 64; d <<= 1) {
            int o = __shfl_up(v, d);
            if (lane >= d) v += o;
        }
        if (lane == 63) s_wsum[wid] = v;
        __syncthreads();
        int base = 0;
        #pragma unroll
        for (int w = 0; w < NWAVES; ++w) base += (w < wid) ? s_wsum[w] : 0;
        int off = base + v - c;                   // exclusive prefix
        if (f0) s_idx[off++] = (2 * tid) * NU;
        if (f1) s_idx[off]   = (2 * tid + 1) * NU;
        if (tid == BLK - 1) s_cnt = base + v;
        __syncthreads();

        int cnt = s_cnt;
        if (cnt == 0) {
            size_t  elems  = (size_t)(TSTEPS - t) * NU;
            float4* p      = (float4*)(outb + (size_t)t * NU);
            int     chunks = (int)(elems / 4);
            float4  zz; zz.x = zz.y = zz.z = zz.w = 0.0f;
            for (int i = tid; i < chunks; i += BLK) p[i] = zz;
            return;
        }

        float I0 = 0.0f, I1 = 0.0f;
        const float* Wc = W + tid;
        int i = 0;
        for (; i + 4 <= cnt; i += 4) {
            const float* r0 = Wc + s_idx[i];
            const float* r1 = Wc + s_idx[i + 1];
            const float* r2 = Wc + s_idx[i + 2];
            const float* r3 = Wc + s_idx[i + 3];
            float a0 = r0[0], b0 = r0[BLK];
            float a1 = r1[0], b1 = r1[BLK];
            float a2 = r2[0], b2 = r2[BLK];
            float a3 = r3[0], b3 = r3[BLK];
            I0 += a0; I0 += a1; I0 += a2; I0 += a3;   // order preserved
            I1 += b0; I1 += b1; I1 += b2; I1 += b3;
        }
        for (; i < cnt; ++i) {
            const float* r = Wc + s_idx[i];
            I0 += r[0];
            I1 += r[BLK];
        }

        float d0 = 0.90483741803595952f * V0;     // one rounding
        float d1 = 0.90483741803595952f * V1r;
        asm volatile("" : "+v"(d0), "+v"(d1));    // forbid fma-contraction
        float nv0 = (z0 ? 0.0f : d0) + I0;        // one rounding
        float nv1 = (z1 ? 0.0f : d1) + I1;
        V0 = nv0; V1r = nv1;
        z0 = nv0 > 1.0f;
        z1 = nv1 > 1.0f;

        float* po = outb + (size_t)t * NU;
        po[n0] = z0 ? 1.0f : 0.0f;
        po[n1] = z1 ? 1.0f : 0.0f;
        s_flag[n0] = (unsigned char)z0;
        s_flag[n1] = (unsigned char)z1;
        __syncthreads();
    }
}

// ---------------- Fallback: round-4 fused kernel (proven) ------------------
__global__ __launch_bounds__(BLK) void lif_fused(
    const float* __restrict__ x,
    const float* __restrict__ W,
    float* __restrict__ out)
{
    const int b    = blockIdx.x;
    const int tid  = threadIdx.x;
    const int lane = tid & 63;
    const int wid  = tid >> 6;

    __shared__ float         s_x[NU];
    __shared__ int           s_idx[NU];
    __shared__ unsigned char s_flag[NU];
    __shared__ int           s_wsum[NWAVES];
    __shared__ int           s_cnt;

    const int n0 = tid;
    const int n1 = tid + BLK;
    float* outb = out + (size_t)b * TSTEPS * NU;

    {
        float x0 = x[(size_t)b * NU + n0];
        float x1 = x[(size_t)b * NU + n1];
        s_x[n0] = x0; s_x[n1] = x1;
        outb[n0] = x0; outb[n1] = x1;
    }
    __syncthreads();

    float I0 = 0.0f, I1 = 0.0f;
    {
        const float* Wc = W + tid;
        #pragma unroll 8
        for (int k = 0; k < NU; ++k) {
            float xk = s_x[k];
            const float* wr = Wc + (size_t)k * NU;
            I0 = __builtin_fmaf(xk, wr[0],   I0);
            I1 = __builtin_fmaf(xk, wr[BLK], I1);
        }
    }

    float V0 = 0.0f, V1 = 0.0f;
    int   z0 = 0,    z1 = 0;

    for (int t = 1; t < TSTEPS; ++t) {
        if (t >= 2) {
            int f0 = s_flag[2 * tid];
            int f1 = s_flag[2 * tid + 1];
            int c  = f0 + f1;
            int v  = c;
            #pragma unroll
            for (int d = 1; d < 64; d <<= 1) {
                int o = __shfl_up(v, d);
                if (lane >= d) v += o;
            }
            if (lane == 63) s_wsum[wid] = v;
            __syncthreads();
            int base = 0;
            #pragma unroll
            for (int w = 0; w < NWAVES; ++w) base += (w < wid) ? s_wsum[w] : 0;
            int off = base + v - c;
            if (f0) s_idx[off++] = 2 * tid;
            if (f1) s_idx[off]   = 2 * tid + 1;
            if (tid == BLK - 1) s_cnt = base + v;
            __syncthreads();

            int cnt = s_cnt;
            if (cnt == 0) {
                size_t  elems  = (size_t)(TSTEPS - t) * NU;
                float4* p      = (float4*)(outb + (size_t)t * NU);
                int     chunks = (int)(elems / 4);
                float4  zz; zz.x = zz.y = zz.z = zz.w = 0.0f;
                for (int i = tid; i < chunks; i += BLK) p[i] = zz;
                return;
            }

            I0 = 0.0f; I1 = 0.0f;
            const float* Wc = W + tid;
            int i = 0;
            for (; i + 2 <= cnt; i += 2) {
                const float* r0 = Wc + (size_t)s_idx[i]     * NU;
                const float* r1 = Wc + (size_t)s_idx[i + 1] * NU;
                float a0 = r0[0], b0 = r0[BLK];
                float a1 = r1[0], b1 = r1[BLK];
                I0 += a0; I0 += a1;
                I1 += b0; I1 += b1;
            }
            for (; i < cnt; ++i) {
                const float* r = Wc + (size_t)s_idx[i] * NU;
                I0 += r[0];
                I1 += r[BLK];
            }
        }

        float d0 = 0.90483741803595952f * V0;
        float d1 = 0.90483741803595952f * V1;
        asm volatile("" : "+v"(d0), "+v"(d1));
        float nv0 = (z0 ? 0.0f : d0) + I0;
        float nv1 = (z1 ? 0.0f : d1) + I1;
        V0 = nv0; V1 = nv1;
        z0 = nv0 > 1.0f;
        z1 = nv1 > 1.0f;

        float* po = outb + (size_t)t * NU;
        po[n0] = z0 ? 1.0f : 0.0f;
        po[n1] = z1 ? 1.0f : 0.0f;
        s_flag[n0] = (unsigned char)z0;
        s_flag[n1] = (unsigned char)z1;
        __syncthreads();
    }
}

extern "C" void kernel_launch(void* const* d_in, const int* in_sizes, int n_in,
                              void* d_out, int out_size, void* d_ws, size_t ws_size,
                              hipStream_t stream) {
    const float* x = (const float*)d_in[0];   // (256, 2048) fp32
    const float* W = (const float*)d_in[1];   // (2048, 2048) fp32
    if (n_in >= 2 && in_sizes[0] == NU * NU && in_sizes[1] == BATCHSZ * NU) {
        const float* t = x; x = W; W = t;     // defensive input-order swap
    }
    float* out = (float*)d_out;               // (B, T, N) fp32

    const size_t need = (size_t)BATCHSZ * NU * sizeof(float);   // 2 MB
    if (ws_size >= need) {
        float* V1 = (float*)d_ws;
        hipLaunchKernelGGL(lif_dense_v1,
                           dim3(512), dim3(128), 0, stream,
                           x, W, V1);
        hipLaunchKernelGGL(lif_recurrence,
                           dim3(BATCHSZ), dim3(BLK), 0, stream,
                           x, W, V1, out);
    } else {
        hipLaunchKernelGGL(lif_fused, dim3(BATCHSZ), dim3(BLK), 0, stream,
                           x, W, out);
    }
}